// Round 2
// baseline (1041.390 us; speedup 1.0000x reference)
//
#include <hip/hip_runtime.h>

// Problem constants (from reference)
constexpr int B_     = 4;
constexpr int N_UP   = 16384;
constexpr int N_DOWN = 4096;
constexpr int C_UP_  = 384;
constexpr int C_DOWN_= 512;
constexpr int C_OUT_ = 512;

// ---------------------------------------------------------------------------
// Kernel 1: 3-NN over down_points, per-batch, down points staged in LDS.
// One thread per up point. Writes idx[3] (int) and normalized w[3] (float).
//
// CRITICAL: the reference computes dist = ||u||^2 + ||d||^2 - 2*u.d in f32
// with no FMA (np.einsum default path). Near-ties at the 3rd/4th neighbor
// boundary flip if our distance rounding differs, and one flip costs O(1)
// in the output. So we replicate the formula bit-for-bit:
//   u2 = (x*x + y*y) + z*z          (f32, no contract)
//   d2 = (x*x + y*y) + z*z          (precomputed per down point)
//   cr = (x*x' + y*y') + z*z'
//   dist = (u2 + d2) - 2*cr
// and weights w_i = 1/(d_i+eps), normalized by per-element DIVISION.
// ---------------------------------------------------------------------------
__launch_bounds__(256)
__global__ void knn_kernel(const float* __restrict__ up_pts,    // [B, N_UP, 3]
                           const float* __restrict__ down_pts,  // [B, N_DOWN, 3]
                           int*  __restrict__ idx_out,          // [B*N_UP, 3]
                           float* __restrict__ w_out)           // [B*N_UP, 3]
{
#pragma clang fp contract(off)
    __shared__ float sx[N_DOWN];
    __shared__ float sy[N_DOWN];
    __shared__ float sz[N_DOWN];
    __shared__ float sd2[N_DOWN];

    const int b = blockIdx.y;
    const float* dp = down_pts + (size_t)b * N_DOWN * 3;
    for (int i = threadIdx.x; i < N_DOWN; i += blockDim.x) {
        const float x = dp[i * 3 + 0];
        const float y = dp[i * 3 + 1];
        const float z = dp[i * 3 + 2];
        sx[i] = x;
        sy[i] = y;
        sz[i] = z;
        sd2[i] = (x * x + y * y) + z * z;   // ref order, no fma
    }
    __syncthreads();

    const int n = blockIdx.x * blockDim.x + threadIdx.x;   // 0..N_UP-1
    const int g = b * N_UP + n;
    const float px = up_pts[(size_t)g * 3 + 0];
    const float py = up_pts[(size_t)g * 3 + 1];
    const float pz = up_pts[(size_t)g * 3 + 2];
    const float u2 = (px * px + py * py) + pz * pz;        // ref order, no fma

    float d0 = 1e30f, d1 = 1e30f, d2 = 1e30f;
    int   i0 = 0,     i1 = 0,     i2 = 0;

    for (int m = 0; m < N_DOWN; ++m) {
        const float cr = (px * sx[m] + py * sy[m]) + pz * sz[m];  // ref order
        const float d  = (u2 + sd2[m]) - 2.0f * cr;               // ref order
        if (d < d2) {
            if (d < d1) {
                if (d < d0) { d2 = d1; i2 = i1; d1 = d0; i1 = i0; d0 = d; i0 = m; }
                else        { d2 = d1; i2 = i1; d1 = d;  i1 = m; }
            } else          { d2 = d;  i2 = m; }
        }
    }

    const float w0 = 1.0f / (d0 + 1e-8f);
    const float w1 = 1.0f / (d1 + 1e-8f);
    const float w2 = 1.0f / (d2 + 1e-8f);
    const float s  = (w0 + w1) + w2;    // ref sum order
    idx_out[(size_t)g * 3 + 0] = i0;
    idx_out[(size_t)g * 3 + 1] = i1;
    idx_out[(size_t)g * 3 + 2] = i2;
    w_out[(size_t)g * 3 + 0] = w0 / s;  // ref: elementwise divide
    w_out[(size_t)g * 3 + 1] = w1 / s;
    w_out[(size_t)g * 3 + 2] = w2 / s;
}

// ---------------------------------------------------------------------------
// Kernel 2/3: f32 SGEMM  C[m,n] = sum_k A[m,k]*W[n,k] + bias[n]  (+ interp)
// 64x64 block tile, BK=16, 256 threads, 4x4 micro-tile per thread.
// INTERP epilogue adds sum_{j<3} w[m][j] * down_f[b*N_DOWN + idx[m][j], n].
// ---------------------------------------------------------------------------
template<bool INTERP>
__launch_bounds__(256)
__global__ void sgemm_kernel(const float* __restrict__ A,   // [M, Kdim]
                             const int Kdim,
                             const float* __restrict__ W,   // [N, Kdim]
                             const float* __restrict__ bias,// [N]
                             float* __restrict__ C,         // [M, N]
                             const int N,
                             const int* __restrict__ knn_idx,   // [M,3]
                             const float* __restrict__ knn_w,   // [M,3]
                             const float* __restrict__ down_f)  // [B*N_DOWN, N]
{
    __shared__ __align__(16) float As[16][68];
    __shared__ __align__(16) float Ws[16][68];

    const int tid = threadIdx.x;
    const int tx  = tid & 15;   // n-direction
    const int ty  = tid >> 4;   // m-direction
    const int m0  = blockIdx.y * 64;
    const int n0  = blockIdx.x * 64;
    const int lr  = tid >> 2;         // 0..63  (tile row for staging)
    const int lk  = (tid & 3) * 4;    // 0,4,8,12 (k offset for staging)

    float acc[4][4] = {};

    for (int k0 = 0; k0 < Kdim; k0 += 16) {
        const float4 a4 = *reinterpret_cast<const float4*>(
            &A[(size_t)(m0 + lr) * Kdim + k0 + lk]);
        const float4 w4 = *reinterpret_cast<const float4*>(
            &W[(size_t)(n0 + lr) * Kdim + k0 + lk]);
        __syncthreads();
        As[lk + 0][lr] = a4.x; As[lk + 1][lr] = a4.y;
        As[lk + 2][lr] = a4.z; As[lk + 3][lr] = a4.w;
        Ws[lk + 0][lr] = w4.x; Ws[lk + 1][lr] = w4.y;
        Ws[lk + 2][lr] = w4.z; Ws[lk + 3][lr] = w4.w;
        __syncthreads();

#pragma unroll
        for (int kk = 0; kk < 16; ++kk) {
            const float4 av = *reinterpret_cast<const float4*>(&As[kk][ty * 4]);
            const float4 wv = *reinterpret_cast<const float4*>(&Ws[kk][tx * 4]);
            const float a[4] = {av.x, av.y, av.z, av.w};
            const float w[4] = {wv.x, wv.y, wv.z, wv.w};
#pragma unroll
            for (int i = 0; i < 4; ++i)
#pragma unroll
                for (int j = 0; j < 4; ++j)
                    acc[i][j] += a[i] * w[j];
        }
    }

    const int ncol = n0 + tx * 4;
    const float4 bv = *reinterpret_cast<const float4*>(&bias[ncol]);

#pragma unroll
    for (int i = 0; i < 4; ++i) {
        const int mg = m0 + ty * 4 + i;
        float4 r;
        r.x = acc[i][0] + bv.x;
        r.y = acc[i][1] + bv.y;
        r.z = acc[i][2] + bv.z;
        r.w = acc[i][3] + bv.w;
        if (INTERP) {
            const int bb   = mg >> 14;               // / N_UP (16384)
            const int base = bb * N_DOWN;
            const int j0 = knn_idx[(size_t)mg * 3 + 0];
            const int j1 = knn_idx[(size_t)mg * 3 + 1];
            const int j2 = knn_idx[(size_t)mg * 3 + 2];
            const float w0 = knn_w[(size_t)mg * 3 + 0];
            const float w1 = knn_w[(size_t)mg * 3 + 1];
            const float w2 = knn_w[(size_t)mg * 3 + 2];
            const float4 f0 = *reinterpret_cast<const float4*>(
                &down_f[(size_t)(base + j0) * N + ncol]);
            const float4 f1 = *reinterpret_cast<const float4*>(
                &down_f[(size_t)(base + j1) * N + ncol]);
            const float4 f2 = *reinterpret_cast<const float4*>(
                &down_f[(size_t)(base + j2) * N + ncol]);
            r.x += w0 * f0.x + w1 * f1.x + w2 * f2.x;
            r.y += w0 * f0.y + w1 * f1.y + w2 * f2.y;
            r.z += w0 * f0.z + w1 * f1.z + w2 * f2.z;
            r.w += w0 * f0.w + w1 * f1.w + w2 * f2.w;
        }
        *reinterpret_cast<float4*>(&C[(size_t)mg * N + ncol]) = r;
    }
}

// ---------------------------------------------------------------------------
extern "C" void kernel_launch(void* const* d_in, const int* in_sizes, int n_in,
                              void* d_out, int out_size, void* d_ws, size_t ws_size,
                              hipStream_t stream) {
    const float* up_points     = (const float*)d_in[0];
    const float* up_features   = (const float*)d_in[1];
    const float* down_points   = (const float*)d_in[2];
    const float* down_features = (const float*)d_in[3];
    const float* W_up          = (const float*)d_in[4];
    const float* b_up          = (const float*)d_in[5];
    const float* W_down        = (const float*)d_in[6];
    const float* b_down        = (const float*)d_in[7];
    float* out = (float*)d_out;

    char* ws = (char*)d_ws;
    // workspace layout: down_f [B*N_DOWN, C_OUT] f32, knn_idx [B*N_UP,3] i32,
    // knn_w [B*N_UP,3] f32  -> ~35 MB total
    float* down_f  = (float*)ws;
    size_t off     = (size_t)B_ * N_DOWN * C_OUT_ * sizeof(float);
    int*   knn_idx = (int*)(ws + off);
    off += (size_t)B_ * N_UP * 3 * sizeof(int);
    float* knn_w   = (float*)(ws + off);

    // 1) KNN (independent of GEMMs)
    knn_kernel<<<dim3(N_UP / 256, B_), 256, 0, stream>>>(
        up_points, down_points, knn_idx, knn_w);

    // 2) down_f = down_features @ W_down^T + b_down   [B*N_DOWN, C_OUT]
    sgemm_kernel<false><<<dim3(C_OUT_ / 64, (B_ * N_DOWN) / 64), 256, 0, stream>>>(
        down_features, C_DOWN_, W_down, b_down, down_f, C_OUT_,
        nullptr, nullptr, nullptr);

    // 3) out = up_features @ W_up^T + b_up + interp(down_f)
    sgemm_kernel<true><<<dim3(C_OUT_ / 64, (B_ * N_UP) / 64), 256, 0, stream>>>(
        up_features, C_UP_, W_up, b_up, out, C_OUT_,
        knn_idx, knn_w, down_f);
}

// Round 3
// 480.252 us; speedup vs baseline: 2.1684x; 2.1684x over previous
//
#include <hip/hip_runtime.h>

// Problem constants (from reference)
constexpr int B_     = 4;
constexpr int N_UP   = 16384;
constexpr int N_DOWN = 4096;
constexpr int C_UP_  = 384;
constexpr int C_DOWN_= 512;
constexpr int C_OUT_ = 512;

// KNN chunking
constexpr int S_CHUNKS = 16;               // candidate chunks
constexpr int CH       = N_DOWN / S_CHUNKS; // 256 candidates per chunk

typedef __attribute__((ext_vector_type(8))) short bf16x8;
typedef __attribute__((ext_vector_type(4))) float f32x4;

// f32 -> bf16 round-to-nearest-even (bit-exact, no API dependence)
__device__ inline unsigned short f2bf(float f) {
    unsigned int u = __float_as_uint(f);
    return (unsigned short)((u + 0x7FFFu + ((u >> 16) & 1u)) >> 16);
}

// async global->LDS, 16B per lane. HW: dest = wave-uniform base + lane*16,
// so lds must be computed as base + lane*16 in lane order (it is, below).
__device__ inline void load_lds_128(const void* g, void* l) {
    __builtin_amdgcn_global_load_lds(
        (const __attribute__((address_space(1))) unsigned int*)g,
        (__attribute__((address_space(3))) unsigned int*)l, 16, 0, 0);
}

// ---------------------------------------------------------------------------
// pts4[b][m] = {x, y, z, (x*x+y*y)+z*z}   (ref rounding order, no contract)
// ---------------------------------------------------------------------------
__global__ void prep_pts4(const float* __restrict__ down_pts, float4* __restrict__ pts4) {
#pragma clang fp contract(off)
    const int i = blockIdx.x * 256 + threadIdx.x;   // 0 .. B*N_DOWN-1
    const float x = down_pts[i * 3 + 0];
    const float y = down_pts[i * 3 + 1];
    const float z = down_pts[i * 3 + 2];
    float4 p; p.x = x; p.y = y; p.z = z; p.w = (x * x + y * y) + z * z;
    pts4[i] = p;
}

// ---------------------------------------------------------------------------
// Per-chunk exact top-3. Grid (N_UP/512, B, S_CHUNKS); 2 queries per thread.
// dist = (u2 + d2) - 2*((px*sx+py*sy)+pz*sz)  -- bit-identical to np ref.
// ---------------------------------------------------------------------------
__launch_bounds__(256)
__global__ void knn_chunk(const float* __restrict__ up_pts,   // [B,N_UP,3]
                          const float4* __restrict__ pts4,    // [B,N_DOWN]
                          float* __restrict__ part_d,         // [B*N_UP, S*3]
                          int*   __restrict__ part_i)
{
#pragma clang fp contract(off)
    __shared__ float4 sp[CH];

    const int b = blockIdx.y;
    const int s = blockIdx.z;
    const int mbase = s * CH;
    const float4* src = pts4 + (size_t)b * N_DOWN + mbase;
    if (threadIdx.x < CH) sp[threadIdx.x] = src[threadIdx.x];
    __syncthreads();

    const int n0 = blockIdx.x * 512;
    const int g0 = b * N_UP + n0 + threadIdx.x;
    const int g1 = g0 + 256;

    const float ax = up_pts[(size_t)g0 * 3 + 0];
    const float ay = up_pts[(size_t)g0 * 3 + 1];
    const float az = up_pts[(size_t)g0 * 3 + 2];
    const float au = (ax * ax + ay * ay) + az * az;
    const float bx = up_pts[(size_t)g1 * 3 + 0];
    const float by = up_pts[(size_t)g1 * 3 + 1];
    const float bz = up_pts[(size_t)g1 * 3 + 2];
    const float bu = (bx * bx + by * by) + bz * bz;

    float a0 = 1e30f, a1 = 1e30f, a2 = 1e30f;  int ia0 = 0, ia1 = 0, ia2 = 0;
    float b0 = 1e30f, b1 = 1e30f, b2 = 1e30f;  int ib0 = 0, ib1 = 0, ib2 = 0;

    for (int m = 0; m < CH; ++m) {
        const float4 p = sp[m];
        const int gi = mbase + m;
        const float cra = (ax * p.x + ay * p.y) + az * p.z;
        const float da  = (au + p.w) - 2.0f * cra;
        if (da < a2) {
            if (da < a1) {
                if (da < a0) { a2 = a1; ia2 = ia1; a1 = a0; ia1 = ia0; a0 = da; ia0 = gi; }
                else         { a2 = a1; ia2 = ia1; a1 = da; ia1 = gi; }
            } else           { a2 = da; ia2 = gi; }
        }
        const float crb = (bx * p.x + by * p.y) + bz * p.z;
        const float db  = (bu + p.w) - 2.0f * crb;
        if (db < b2) {
            if (db < b1) {
                if (db < b0) { b2 = b1; ib2 = ib1; b1 = b0; ib1 = ib0; b0 = db; ib0 = gi; }
                else         { b2 = b1; ib2 = ib1; b1 = db; ib1 = gi; }
            } else           { b2 = db; ib2 = gi; }
        }
    }

    float* pd = part_d + (size_t)g0 * (S_CHUNKS * 3) + s * 3;
    int*   pi = part_i + (size_t)g0 * (S_CHUNKS * 3) + s * 3;
    pd[0] = a0; pd[1] = a1; pd[2] = a2;
    pi[0] = ia0; pi[1] = ia1; pi[2] = ia2;
    pd = part_d + (size_t)g1 * (S_CHUNKS * 3) + s * 3;
    pi = part_i + (size_t)g1 * (S_CHUNKS * 3) + s * 3;
    pd[0] = b0; pd[1] = b1; pd[2] = b2;
    pi[0] = ib0; pi[1] = ib1; pi[2] = ib2;
}

// ---------------------------------------------------------------------------
// Merge S*3 exact candidates (ascending chunk = ascending index => identical
// tie-breaks to the full scan), compute normalized inverse-distance weights.
// ---------------------------------------------------------------------------
__launch_bounds__(256)
__global__ void knn_merge(const float* __restrict__ part_d,
                          const int*   __restrict__ part_i,
                          int*  __restrict__ idx_out,   // [B*N_UP,3]
                          float* __restrict__ w_out)    // [B*N_UP,3]
{
    const int g = blockIdx.x * 256 + threadIdx.x;
    const float4* pd = (const float4*)(part_d + (size_t)g * (S_CHUNKS * 3));
    const int4*   pi = (const int4*)(part_i + (size_t)g * (S_CHUNKS * 3));

    float d0 = 1e30f, d1 = 1e30f, d2 = 1e30f;
    int   i0 = 0,     i1 = 0,     i2 = 0;

#pragma unroll
    for (int q = 0; q < (S_CHUNKS * 3) / 4; ++q) {
        const float4 dv = pd[q];
        const int4   iv = pi[q];
        const float dd[4] = {dv.x, dv.y, dv.z, dv.w};
        const int   ii[4] = {iv.x, iv.y, iv.z, iv.w};
#pragma unroll
        for (int j = 0; j < 4; ++j) {
            const float d = dd[j];
            const int   m = ii[j];
            if (d < d2) {
                if (d < d1) {
                    if (d < d0) { d2 = d1; i2 = i1; d1 = d0; i1 = i0; d0 = d; i0 = m; }
                    else        { d2 = d1; i2 = i1; d1 = d;  i1 = m; }
                } else          { d2 = d;  i2 = m; }
            }
        }
    }

    const float w0 = 1.0f / (d0 + 1e-8f);
    const float w1 = 1.0f / (d1 + 1e-8f);
    const float w2 = 1.0f / (d2 + 1e-8f);
    const float s  = (w0 + w1) + w2;
    idx_out[(size_t)g * 3 + 0] = i0;
    idx_out[(size_t)g * 3 + 1] = i1;
    idx_out[(size_t)g * 3 + 2] = i2;
    w_out[(size_t)g * 3 + 0] = w0 / s;
    w_out[(size_t)g * 3 + 1] = w1 / s;
    w_out[(size_t)g * 3 + 2] = w2 / s;
}

// ---------------------------------------------------------------------------
// f32 -> bf16 conversion, 4 elements/thread
// ---------------------------------------------------------------------------
__launch_bounds__(256)
__global__ void cvt_bf16(const float* __restrict__ src, unsigned short* __restrict__ dst) {
    const size_t i = (size_t)blockIdx.x * 256 + threadIdx.x;
    const float4 v = ((const float4*)src)[i];
    ushort4 o;
    o.x = f2bf(v.x); o.y = f2bf(v.y); o.z = f2bf(v.z); o.w = f2bf(v.w);
    ((ushort4*)dst)[i] = o;
}

// ---------------------------------------------------------------------------
// bf16 MFMA GEMM: C[m,n] = sum_k A[m,k]*W[n,k] (+bias) (+interp gather)
// 128x128 tile, BK=32, 256 threads = 4 waves (2x2 of 64x64), 16x16x32 MFMA.
// m97-style global_load_lds width-16 staging.
// ---------------------------------------------------------------------------
template<bool INTERP>
__launch_bounds__(256)
__global__ void gemm_bf16(const unsigned short* __restrict__ A,  // [M,K] bf16
                          const unsigned short* __restrict__ W,  // [N,K] bf16
                          const float* __restrict__ bias,        // [N]
                          float* __restrict__ C,                 // [M,N] f32
                          const int K, const int N,
                          const int* __restrict__ knn_idx,       // [M,3]
                          const float* __restrict__ knn_w,       // [M,3]
                          const float* __restrict__ down_f)      // [B*N_DOWN,N]
{
    __shared__ __align__(16) unsigned short As[128 * 32];
    __shared__ __align__(16) unsigned short Bs[128 * 32];
    __shared__ int   sI[128 * 3];
    __shared__ float sV[128 * 3];

    const int tid  = threadIdx.x;
    const int lane = tid & 63;
    const int wv   = tid >> 6;
    const int wrow = (wv >> 1) * 64;
    const int wcol = (wv & 1) * 64;
    const int quad = lane >> 4;
    const int l16  = lane & 15;
    const int m0   = blockIdx.y * 128;
    const int n0   = blockIdx.x * 128;

    if (INTERP) {
        for (int t = tid; t < 384; t += 256) {
            sI[t] = knn_idx[(size_t)m0 * 3 + t];
            sV[t] = knn_w[(size_t)m0 * 3 + t];
        }
    }

    f32x4 acc[4][4];
#pragma unroll
    for (int i = 0; i < 4; ++i)
#pragma unroll
        for (int j = 0; j < 4; ++j) {
            acc[i][j][0] = 0.f; acc[i][j][1] = 0.f;
            acc[i][j][2] = 0.f; acc[i][j][3] = 0.f;
        }

    // staging geometry: LDS tile is [row][32k] bf16 (64 B rows); each wave
    // covers 2 KiB as two 1 KiB chunks of lane*16.
    const int o0 = wv * 2048 + lane * 16;
    const int o1 = o0 + 1024;
    const int r0 = o0 >> 6, kk0 = o0 & 63;
    const int r1 = o1 >> 6, kk1 = o1 & 63;
    const char* Ab = (const char*)A;
    const char* Wb = (const char*)W;
    const size_t Ks = (size_t)K;

    for (int k0 = 0; k0 < K; k0 += 32) {
        __syncthreads();   // previous iter's ds_reads done before overwrite
        load_lds_128(Ab + ((size_t)(m0 + r0) * Ks + k0) * 2 + kk0, (char*)As + o0);
        load_lds_128(Ab + ((size_t)(m0 + r1) * Ks + k0) * 2 + kk1, (char*)As + o1);
        load_lds_128(Wb + ((size_t)(n0 + r0) * Ks + k0) * 2 + kk0, (char*)Bs + o0);
        load_lds_128(Wb + ((size_t)(n0 + r1) * Ks + k0) * 2 + kk1, (char*)Bs + o1);
        __syncthreads();   // vmcnt(0) drained by compiler before barrier

        bf16x8 af[4], bw[4];
#pragma unroll
        for (int i = 0; i < 4; ++i)
            af[i] = *(const bf16x8*)(As + (wrow + i * 16 + l16) * 32 + quad * 8);
#pragma unroll
        for (int j = 0; j < 4; ++j)
            bw[j] = *(const bf16x8*)(Bs + (wcol + j * 16 + l16) * 32 + quad * 8);
#pragma unroll
        for (int i = 0; i < 4; ++i)
#pragma unroll
            for (int j = 0; j < 4; ++j)
                acc[i][j] = __builtin_amdgcn_mfma_f32_16x16x32_bf16(
                    af[i], bw[j], acc[i][j], 0, 0, 0);
    }

    float bv[4];
#pragma unroll
    for (int j = 0; j < 4; ++j) bv[j] = bias[n0 + wcol + j * 16 + l16];

#pragma unroll
    for (int i = 0; i < 4; ++i) {
#pragma unroll
        for (int r = 0; r < 4; ++r) {
            const int row = m0 + wrow + i * 16 + quad * 4 + r;  // C/D: row=quad*4+reg
            float* crow = C + (size_t)row * N;
            if (INTERP) {
                const int lr3  = (row - m0) * 3;
                const int base = (row >> 14) * N_DOWN;          // batch * N_DOWN
                const float w0 = sV[lr3 + 0], w1 = sV[lr3 + 1], w2 = sV[lr3 + 2];
                const float* f0 = down_f + (size_t)(base + sI[lr3 + 0]) * N;
                const float* f1 = down_f + (size_t)(base + sI[lr3 + 1]) * N;
                const float* f2 = down_f + (size_t)(base + sI[lr3 + 2]) * N;
#pragma unroll
                for (int j = 0; j < 4; ++j) {
                    const int c = n0 + wcol + j * 16 + l16;     // C/D: col=lane&15
                    crow[c] = acc[i][j][r] + bv[j] + w0 * f0[c] + w1 * f1[c] + w2 * f2[c];
                }
            } else {
#pragma unroll
                for (int j = 0; j < 4; ++j) {
                    const int c = n0 + wcol + j * 16 + l16;
                    crow[c] = acc[i][j][r] + bv[j];
                }
            }
        }
    }
}

// ---------------------------------------------------------------------------
extern "C" void kernel_launch(void* const* d_in, const int* in_sizes, int n_in,
                              void* d_out, int out_size, void* d_ws, size_t ws_size,
                              hipStream_t stream) {
    const float* up_points     = (const float*)d_in[0];
    const float* up_features   = (const float*)d_in[1];
    const float* down_points   = (const float*)d_in[2];
    const float* down_features = (const float*)d_in[3];
    const float* W_up          = (const float*)d_in[4];
    const float* b_up          = (const float*)d_in[5];
    const float* W_down        = (const float*)d_in[6];
    const float* b_down        = (const float*)d_in[7];
    float* out = (float*)d_out;

    // workspace layout (all offsets 256B-aligned by construction)
    char* ws = (char*)d_ws;
    size_t off = 0;
    float* down_f = (float*)(ws + off);             off += (size_t)B_ * N_DOWN * C_OUT_ * 4;      // 33.6 MB
    int*   knn_idx = (int*)(ws + off);              off += (size_t)B_ * N_UP * 3 * 4;             // 0.8 MB
    float* knn_w   = (float*)(ws + off);            off += (size_t)B_ * N_UP * 3 * 4;             // 0.8 MB
    float* part_d  = (float*)(ws + off);            off += (size_t)B_ * N_UP * S_CHUNKS * 3 * 4;  // 12.6 MB
    int*   part_i  = (int*)(ws + off);              off += (size_t)B_ * N_UP * S_CHUNKS * 3 * 4;  // 12.6 MB
    float4* pts4   = (float4*)(ws + off);           off += (size_t)B_ * N_DOWN * 16;              // 0.26 MB
    unsigned short* upf_bf = (unsigned short*)(ws + off); off += (size_t)B_ * N_UP * C_UP_ * 2;   // 50.3 MB
    unsigned short* dnf_bf = (unsigned short*)(ws + off); off += (size_t)B_ * N_DOWN * C_DOWN_ * 2; // 16.8 MB
    unsigned short* wup_bf = (unsigned short*)(ws + off); off += (size_t)C_OUT_ * C_UP_ * 2;      // 0.4 MB
    unsigned short* wdn_bf = (unsigned short*)(ws + off); off += (size_t)C_OUT_ * C_DOWN_ * 2;    // 0.5 MB

    // 1) KNN pipeline
    prep_pts4<<<(B_ * N_DOWN) / 256, 256, 0, stream>>>(down_points, pts4);
    knn_chunk<<<dim3(N_UP / 512, B_, S_CHUNKS), 256, 0, stream>>>(
        up_points, pts4, part_d, part_i);
    knn_merge<<<(B_ * N_UP) / 256, 256, 0, stream>>>(part_d, part_i, knn_idx, knn_w);

    // 2) f32 -> bf16 conversions
    cvt_bf16<<<(B_ * N_UP * C_UP_) / 1024, 256, 0, stream>>>(up_features, upf_bf);
    cvt_bf16<<<(B_ * N_DOWN * C_DOWN_) / 1024, 256, 0, stream>>>(down_features, dnf_bf);
    cvt_bf16<<<(C_OUT_ * C_UP_) / 1024, 256, 0, stream>>>(W_up, wup_bf);
    cvt_bf16<<<(C_OUT_ * C_DOWN_) / 1024, 256, 0, stream>>>(W_down, wdn_bf);

    // 3) down_f = down_features @ W_down^T + b_down   [B*N_DOWN, 512]
    gemm_bf16<false><<<dim3(C_OUT_ / 128, (B_ * N_DOWN) / 128), 256, 0, stream>>>(
        dnf_bf, wdn_bf, b_down, down_f, C_DOWN_, C_OUT_, nullptr, nullptr, nullptr);

    // 4) out = up_features @ W_up^T + b_up + interp(down_f)   [B*N_UP, 512]
    gemm_bf16<true><<<dim3(C_OUT_ / 128, (B_ * N_UP) / 128), 256, 0, stream>>>(
        upf_bf, wup_bf, b_up, out, C_UP_, C_OUT_, knn_idx, knn_w, down_f);
}